// Round 16
// baseline (461.267 us; speedup 1.0000x reference)
//
#include <hip/hip_runtime.h>

namespace {
constexpr int N_ = 16, C_ = 32, V_ = 512, T_ = 64;
constexpr int H_ = 4, D_ = 16, OC_ = 64;
constexpr int EMB_ = 64;
constexpr int GCIN_ = 7 * C_;         // 224
constexpr int TV_ = T_ * V_;          // 32768 elements per slice
}

typedef _Float16 f16x8 __attribute__((ext_vector_type(8)));
typedef _Float16 f16x4 __attribute__((ext_vector_type(4)));
typedef _Float16 f16x2 __attribute__((ext_vector_type(2)));
typedef float f32x4 __attribute__((ext_vector_type(4)));

// ---------------------------------------------------------------------------
// Kernel 1: per-(n,h) attention rows. att[n,h,t,p] = softmax_p(q_t . k_p / 4)
// ---------------------------------------------------------------------------
__global__ __launch_bounds__(64) void att_kernel(
    const float* __restrict__ t_in, const float* __restrict__ factors,
    const float* __restrict__ Wq, const float* __restrict__ Wk,
    float* __restrict__ att)
{
    const int n = blockIdx.x >> 2;
    const int h = blockIdx.x & 3;
    const int t = threadIdx.x;   // 0..63

    __shared__ float wq_l[EMB_][D_];
    __shared__ float wk_l[EMB_][D_];
    __shared__ float k_l[T_][D_ + 1];

#pragma unroll
    for (int d = 0; d < D_; ++d) {
        wq_l[t][d] = Wq[(h * EMB_ + t) * D_ + d];
        wk_l[t][d] = Wk[(h * EMB_ + t) * D_ + d];
    }
    __syncthreads();

    const float tv = t_in[n * T_ + t];
    const float fh = factors[h];
    float emb[EMB_];
#pragma unroll
    for (int j = 0; j < 32; ++j) {
        float dt = __expf((float)(2 * j) * fh);
        float ph = tv * dt;
        float s, c;
        __sincosf(ph, &s, &c);
        emb[j] = s;
        emb[j + 32] = c;
    }

    float q[D_];
#pragma unroll
    for (int d = 0; d < D_; ++d) {
        float aq = 0.f, ak = 0.f;
#pragma unroll
        for (int f = 0; f < EMB_; ++f) {
            aq += emb[f] * wq_l[f][d];
            ak += emb[f] * wk_l[f][d];
        }
        q[d] = aq;
        k_l[t][d] = ak;
    }
    __syncthreads();

    float L[T_];
    float m = -1e30f;
#pragma unroll
    for (int j = 0; j < T_; ++j) {
        float a = 0.f;
#pragma unroll
        for (int d = 0; d < D_; ++d) a += q[d] * k_l[j][d];
        a *= 0.25f;
        L[j] = a;
        m = fmaxf(m, a);
    }
    float ssum = 0.f;
#pragma unroll
    for (int j = 0; j < T_; ++j) {
        float e = __expf(L[j] - m);
        L[j] = e;
        ssum += e;
    }
    const float inv = 1.f / ssum;
    float* arow = att + (((size_t)(n * H_ + h) * T_ + t) * T_);
#pragma unroll
    for (int j = 0; j < T_; ++j) arow[j] = L[j] * inv;
}

// ---------------------------------------------------------------------------
// Kernel 2: S[n,i,j] = sum_h att[n,h,i,j]
// ---------------------------------------------------------------------------
__global__ __launch_bounds__(256) void sred_kernel(
    const float* __restrict__ att, float* __restrict__ S)
{
    int g = blockIdx.x * 256 + threadIdx.x;
    if (g >= N_ * T_ * T_) return;
    int n = g / (T_ * T_);
    int ij = g - n * (T_ * T_);
    float a = 0.f;
#pragma unroll
    for (int h = 0; h < H_; ++h) a += att[(size_t)(n * H_ + h) * (T_ * T_) + ij];
    S[g] = a;
}

// ---------------------------------------------------------------------------
// Kernel 3: At16[s][w][v] = (f16) A_s[v][w]   (transpose + cast)
// ---------------------------------------------------------------------------
__global__ __launch_bounds__(256) void prepAt_kernel(
    const float* __restrict__ A0, const float* __restrict__ A1,
    const float* __restrict__ A2, _Float16* __restrict__ At16)
{
    const int s = blockIdx.z;
    const float* A = (s == 0) ? A0 : ((s == 1) ? A1 : A2);
    const int v0 = blockIdx.y * 32, w0 = blockIdx.x * 32;
    const int tid = threadIdx.x;
    __shared__ float sT[32][33];
#pragma unroll
    for (int k = 0; k < 4; ++k) {
        int lin = k * 256 + tid;
        int i = lin >> 5, w = lin & 31;
        sT[i][w] = A[(size_t)(v0 + i) * V_ + w0 + w];
    }
    __syncthreads();
#pragma unroll
    for (int k = 0; k < 4; ++k) {
        int lin = k * 256 + tid;
        int j = lin >> 5, i = lin & 31;
        At16[(size_t)s * V_ * V_ + (size_t)(w0 + j) * V_ + v0 + i] = (_Float16)sT[i][j];
    }
}

// ---------------------------------------------------------------------------
// Kernel 3b: residual channels, channel-PAIR interleaved:
// xT[q][t][v][sl] = (f16) x[n0*C + 2q+sl][v][t]   (non-temporal stores)
// ---------------------------------------------------------------------------
__global__ __launch_bounds__(256) void prepxT_kernel(
    const float* __restrict__ x, _Float16* __restrict__ xT, int n0)
{
    const int q = blockIdx.z;            // pair index within chunk
    const int v0 = blockIdx.x * 32;
    const int t0 = blockIdx.y * 32;
    const int tid = threadIdx.x;
    __shared__ float sT0[32][33];
    __shared__ float sT1[32][33];
    const float* xb0 = x + ((size_t)(n0 * C_) + 2 * q) * (size_t)(V_ * T_);
    const float* xb1 = xb0 + (size_t)(V_ * T_);
    {
        int vi = tid >> 3, tq = tid & 7;
        *(float4*)&sT0[vi][tq * 4] = *(const float4*)&xb0[(size_t)(v0 + vi) * T_ + t0 + tq * 4];
        *(float4*)&sT1[vi][tq * 4] = *(const float4*)&xb1[(size_t)(v0 + vi) * T_ + t0 + tq * 4];
    }
    __syncthreads();
    {
        int tj = tid >> 3, vq = tid & 7;
        f16x8 o;
#pragma unroll
        for (int j = 0; j < 4; ++j) {
            o[2 * j]     = (_Float16)sT0[vq * 4 + j][tj];
            o[2 * j + 1] = (_Float16)sT1[vq * 4 + j][tj];
        }
        __builtin_nontemporal_store(o,
            (f16x8*)&xT[(size_t)q * 2 * TV_ + ((size_t)(t0 + tj) * V_ + v0 + vq * 4) * 2]);
    }
}

// ---------------------------------------------------------------------------
// Kernel 3c: Wcat[o][k] f16 (k<224: W_out; k>=224: BN-scaled W_res), bias[o].
// ---------------------------------------------------------------------------
__global__ __launch_bounds__(256) void prepW_kernel(
    const float* __restrict__ W_out, const float* __restrict__ b_out,
    const float* __restrict__ W_res, const float* __restrict__ b_res,
    const float* __restrict__ gamma, const float* __restrict__ beta,
    const float* __restrict__ mean, const float* __restrict__ var,
    _Float16* __restrict__ Wcat, float* __restrict__ bias)
{
    const int tid = threadIdx.x;
    const int o = tid & 63;
    const int kb = tid >> 6;   // 0..3
    const float rs = gamma[o] * rsqrtf(var[o] + 1e-5f);
    for (int kk = 0; kk < 64; ++kk) {
        int k = kb * 64 + kk;
        float w = (k < GCIN_) ? W_out[o * GCIN_ + k] : rs * W_res[o * C_ + (k - GCIN_)];
        Wcat[o * 256 + k] = (_Float16)w;
    }
    if (tid < 64) bias[tid] = b_out[tid] + beta[tid] + rs * (b_res[tid] - mean[tid]);
}

// ---------------------------------------------------------------------------
// Kernel 4: xtT paired: for pair q (slices 2q, 2q+1 sharing n = q>>4):
// XT[q][p][v][sl] = sum_j S[n][p][j] * x[2q+sl][v][j]. B(S) shared by both.
// Non-temporal output stores.
// ---------------------------------------------------------------------------
__global__ __launch_bounds__(256) void xtT_kernel(
    const float* __restrict__ x, const float* __restrict__ S,
    _Float16* __restrict__ XT, int n0)
{
    const int q = blockIdx.y;            // pair index within chunk
    const int n = q >> 4;
    const int lane = threadIdx.x & 63;
    const int wav = threadIdx.x >> 6;
    const int vbase = blockIdx.x * 256 + wav * 64;
    const int row16 = lane & 15;
    const int kg = lane >> 4;

    const float* Sn = S + (size_t)(n0 + n) * (T_ * T_);
    const float* xb0 = x + ((size_t)(n0 * C_) + 2 * q) * (size_t)(V_ * T_);
    const float* xb1 = xb0 + (size_t)(V_ * T_);

    f32x4 acc0[4][4], acc1[4][4];
#pragma unroll
    for (int i = 0; i < 4; ++i)
#pragma unroll
        for (int j = 0; j < 4; ++j) {
            acc0[i][j] = (f32x4){0.f, 0.f, 0.f, 0.f};
            acc1[i][j] = (f32x4){0.f, 0.f, 0.f, 0.f};
        }

#pragma unroll
    for (int ks = 0; ks < 2; ++ks) {
        f16x8 a0[4], a1[4], bf[4];
#pragma unroll
        for (int mt = 0; mt < 4; ++mt) {   // A = x rows (m = v), both slices
            const float* p0 = xb0 + (size_t)(vbase + mt * 16 + row16) * T_ + ks * 32 + kg * 8;
            const float* p1 = xb1 + (size_t)(vbase + mt * 16 + row16) * T_ + ks * 32 + kg * 8;
            float4 u0 = *(const float4*)p0, w0 = *(const float4*)(p0 + 4);
            float4 u1 = *(const float4*)p1, w1 = *(const float4*)(p1 + 4);
            f16x8 t0, t1;
            t0[0] = (_Float16)u0.x; t0[1] = (_Float16)u0.y; t0[2] = (_Float16)u0.z; t0[3] = (_Float16)u0.w;
            t0[4] = (_Float16)w0.x; t0[5] = (_Float16)w0.y; t0[6] = (_Float16)w0.z; t0[7] = (_Float16)w0.w;
            t1[0] = (_Float16)u1.x; t1[1] = (_Float16)u1.y; t1[2] = (_Float16)u1.z; t1[3] = (_Float16)u1.w;
            t1[4] = (_Float16)w1.x; t1[5] = (_Float16)w1.y; t1[6] = (_Float16)w1.z; t1[7] = (_Float16)w1.w;
            a0[mt] = t0; a1[mt] = t1;
        }
#pragma unroll
        for (int nt = 0; nt < 4; ++nt) {   // B = S rows (n = p), shared
            const float* p = Sn + (size_t)(nt * 16 + row16) * T_ + ks * 32 + kg * 8;
            float4 u = *(const float4*)p, w = *(const float4*)(p + 4);
            f16x8 t8;
            t8[0] = (_Float16)u.x; t8[1] = (_Float16)u.y; t8[2] = (_Float16)u.z; t8[3] = (_Float16)u.w;
            t8[4] = (_Float16)w.x; t8[5] = (_Float16)w.y; t8[6] = (_Float16)w.z; t8[7] = (_Float16)w.w;
            bf[nt] = t8;
        }
#pragma unroll
        for (int nt = 0; nt < 4; ++nt)
#pragma unroll
            for (int mt = 0; mt < 4; ++mt) {
                acc0[mt][nt] = __builtin_amdgcn_mfma_f32_16x16x32_f16(a0[mt], bf[nt], acc0[mt][nt], 0, 0, 0);
                acc1[mt][nt] = __builtin_amdgcn_mfma_f32_16x16x32_f16(a1[mt], bf[nt], acc1[mt][nt], 0, 0, 0);
            }
    }

    _Float16* Yq = XT + (size_t)q * 2 * TV_;
#pragma unroll
    for (int nt = 0; nt < 4; ++nt)
#pragma unroll
        for (int mt = 0; mt < 4; ++mt) {
            int p = nt * 16 + row16;
            int v = vbase + mt * 16 + kg * 4;
            f16x8 h;
#pragma unroll
            for (int r = 0; r < 4; ++r) {
                h[2 * r]     = (_Float16)acc0[mt][nt][r];
                h[2 * r + 1] = (_Float16)acc1[mt][nt][r];
            }
            __builtin_nontemporal_store(h, (f16x8*)&Yq[((size_t)p * V_ + v) * 2]);
        }
}

// ---------------------------------------------------------------------------
// Kernel 5: fused double diffusion hop, pair-per-block, interleaved I/O.
// Y-writes via LDS roundtrip with NON-TEMPORAL streaming stores (no L2
// write-allocate). Chain: stage -> bar -> hop1 -> bar -> x1->LDS -> bar ->
// {copyY1 || hop2} -> bar -> x2->LDS -> bar -> copyY2.
// ---------------------------------------------------------------------------
__global__ __launch_bounds__(512) void hopf_kernel(
    const _Float16* __restrict__ At16, _Float16* __restrict__ Hb,
    unsigned long long ASZ)
{
    const int bp = blockIdx.x;  // pair
    const int s = blockIdx.y;   // support
    const int tid = threadIdx.x;
    const int lane = tid & 63;
    const int wav = tid >> 6;
    const int wbase = wav * 64;
    const int row16 = lane & 15;
    const int kg = lane >> 4;

    __shared__ _Float16 xs0[T_ * V_];   // 64 KiB (slice 0)
    __shared__ _Float16 xs1[T_ * V_];   // 64 KiB (slice 1)

    const _Float16* At = At16 + (size_t)s * V_ * V_;
    const _Float16* Xi = Hb + (size_t)bp * 2 * TV_;                     // interleaved
    _Float16* Y1i = Hb + (size_t)(1 + 2 * s) * ASZ + (size_t)bp * 2 * TV_;
    _Float16* Y2i = Hb + (size_t)(2 + 2 * s) * ASZ + (size_t)bp * 2 * TV_;

    const _Float16* ax = At + (size_t)(wbase + row16) * V_ + kg * 8;

    f32x4 acc0[4][4], acc1[4][4];
    f16x8 aC[4], aN[4];

    // ---- stage: read interleaved pair, de-interleave into xs0/xs1 ----
#pragma unroll
    for (int k = 0; k < 8; ++k) {
        int lin = k * 512 + tid;
        int t = lin >> 6;
        int v8 = (lin & 63) << 3;
        const f16x8 lo = *(const f16x8*)&Xi[((size_t)t * V_ + v8) * 2];
        const f16x8 hi = *(const f16x8*)&Xi[((size_t)t * V_ + v8) * 2 + 8];
        f16x8 s0, s1;
        s0[0] = lo[0]; s0[1] = lo[2]; s0[2] = lo[4]; s0[3] = lo[6];
        s0[4] = hi[0]; s0[5] = hi[2]; s0[6] = hi[4]; s0[7] = hi[6];
        s1[0] = lo[1]; s1[1] = lo[3]; s1[2] = lo[5]; s1[3] = lo[7];
        s1[4] = hi[1]; s1[5] = hi[3]; s1[6] = hi[5]; s1[7] = hi[7];
        int byte = (t * V_ + v8) * 2;
        *(f16x8*)((char*)xs0 + (byte ^ ((t & 7) << 4))) = s0;
        *(f16x8*)((char*)xs1 + (byte ^ ((t & 7) << 4))) = s1;
    }
    __syncthreads();

    // ---- hop 1: A global (2-deep), B from both LDS tiles ----
#pragma unroll
    for (int i = 0; i < 4; ++i)
#pragma unroll
        for (int j = 0; j < 4; ++j) {
            acc0[i][j] = (f32x4){0.f, 0.f, 0.f, 0.f};
            acc1[i][j] = (f32x4){0.f, 0.f, 0.f, 0.f};
        }
#pragma unroll
    for (int i = 0; i < 4; ++i)
        aC[i] = *(const f16x8*)(ax + (size_t)i * 16 * V_);

#pragma unroll
    for (int it = 0; it < 16; ++it) {
        const int v0 = it * 32;
        if (it < 15) {
#pragma unroll
            for (int i = 0; i < 4; ++i)
                aN[i] = *(const f16x8*)(ax + (size_t)i * 16 * V_ + v0 + 32);
        }
        f16x8 b0v[4], b1v[4];
#pragma unroll
        for (int nt = 0; nt < 4; ++nt) {
            int t = nt * 16 + row16;
            int byte = (t * V_ + v0 + kg * 8) * 2;
            b0v[nt] = *(const f16x8*)((const char*)xs0 + (byte ^ ((t & 7) << 4)));
            b1v[nt] = *(const f16x8*)((const char*)xs1 + (byte ^ ((t & 7) << 4)));
        }
#pragma unroll
        for (int nt = 0; nt < 4; ++nt)
#pragma unroll
            for (int mt = 0; mt < 4; ++mt) {
                acc0[mt][nt] = __builtin_amdgcn_mfma_f32_16x16x32_f16(aC[mt], b0v[nt], acc0[mt][nt], 0, 0, 0);
                acc1[mt][nt] = __builtin_amdgcn_mfma_f32_16x16x32_f16(aC[mt], b1v[nt], acc1[mt][nt], 0, 0, 0);
            }
#pragma unroll
        for (int i = 0; i < 4; ++i) aC[i] = aN[i];
    }
    __syncthreads();   // all X LDS reads done before overwrite

    // ---- x1 -> LDS (8B swizzled writes, per-slice layout) ----
#pragma unroll
    for (int mt = 0; mt < 4; ++mt)
#pragma unroll
        for (int nt = 0; nt < 4; ++nt) {
            int t = nt * 16 + row16;
            int w = wbase + mt * 16 + kg * 4;
            int byte = (t * V_ + w) * 2;
            f16x4 h0, h1;
            h0[0] = (_Float16)acc0[mt][nt][0]; h0[1] = (_Float16)acc0[mt][nt][1];
            h0[2] = (_Float16)acc0[mt][nt][2]; h0[3] = (_Float16)acc0[mt][nt][3];
            h1[0] = (_Float16)acc1[mt][nt][0]; h1[1] = (_Float16)acc1[mt][nt][1];
            h1[2] = (_Float16)acc1[mt][nt][2]; h1[3] = (_Float16)acc1[mt][nt][3];
            *(f16x4*)((char*)xs0 + (byte ^ ((t & 7) << 4))) = h0;
            *(f16x4*)((char*)xs1 + (byte ^ ((t & 7) << 4))) = h1;
        }
    __syncthreads();

    // ---- Y1 copy: LDS -> global, interleaved, non-temporal ----
#pragma unroll
    for (int k = 0; k < 8; ++k) {
        int lin = k * 512 + tid;
        int t = lin >> 6;
        int v8 = (lin & 63) << 3;
        int byte = (t * V_ + v8) * 2;
        f16x8 s0 = *(const f16x8*)((const char*)xs0 + (byte ^ ((t & 7) << 4)));
        f16x8 s1 = *(const f16x8*)((const char*)xs1 + (byte ^ ((t & 7) << 4)));
        f16x8 lo, hi;
        lo[0] = s0[0]; lo[1] = s1[0]; lo[2] = s0[1]; lo[3] = s1[1];
        lo[4] = s0[2]; lo[5] = s1[2]; lo[6] = s0[3]; lo[7] = s1[3];
        hi[0] = s0[4]; hi[1] = s1[4]; hi[2] = s0[5]; hi[3] = s1[5];
        hi[4] = s0[6]; hi[5] = s1[6]; hi[6] = s0[7]; hi[7] = s1[7];
        __builtin_nontemporal_store(lo, (f16x8*)&Y1i[((size_t)t * V_ + v8) * 2]);
        __builtin_nontemporal_store(hi, (f16x8*)&Y1i[((size_t)t * V_ + v8) * 2 + 8]);
    }

    // ---- hop 2: A global (2-deep), B = x1 from both LDS tiles ----
#pragma unroll
    for (int i = 0; i < 4; ++i)
#pragma unroll
        for (int j = 0; j < 4; ++j) {
            acc0[i][j] = (f32x4){0.f, 0.f, 0.f, 0.f};
            acc1[i][j] = (f32x4){0.f, 0.f, 0.f, 0.f};
        }
#pragma unroll
    for (int i = 0; i < 4; ++i)
        aC[i] = *(const f16x8*)(ax + (size_t)i * 16 * V_);

#pragma unroll
    for (int it = 0; it < 16; ++it) {
        const int v0 = it * 32;
        if (it < 15) {
#pragma unroll
            for (int i = 0; i < 4; ++i)
                aN[i] = *(const f16x8*)(ax + (size_t)i * 16 * V_ + v0 + 32);
        }
        f16x8 b0v[4], b1v[4];
#pragma unroll
        for (int nt = 0; nt < 4; ++nt) {
            int t = nt * 16 + row16;
            int byte = (t * V_ + v0 + kg * 8) * 2;
            b0v[nt] = *(const f16x8*)((const char*)xs0 + (byte ^ ((t & 7) << 4)));
            b1v[nt] = *(const f16x8*)((const char*)xs1 + (byte ^ ((t & 7) << 4)));
        }
#pragma unroll
        for (int nt = 0; nt < 4; ++nt)
#pragma unroll
            for (int mt = 0; mt < 4; ++mt) {
                acc0[mt][nt] = __builtin_amdgcn_mfma_f32_16x16x32_f16(aC[mt], b0v[nt], acc0[mt][nt], 0, 0, 0);
                acc1[mt][nt] = __builtin_amdgcn_mfma_f32_16x16x32_f16(aC[mt], b1v[nt], acc1[mt][nt], 0, 0, 0);
            }
#pragma unroll
        for (int i = 0; i < 4; ++i) aC[i] = aN[i];
    }
    __syncthreads();   // all x1 LDS reads done before overwrite

    // ---- x2 -> LDS ----
#pragma unroll
    for (int mt = 0; mt < 4; ++mt)
#pragma unroll
        for (int nt = 0; nt < 4; ++nt) {
            int t = nt * 16 + row16;
            int w = wbase + mt * 16 + kg * 4;
            int byte = (t * V_ + w) * 2;
            f16x4 h0, h1;
            h0[0] = (_Float16)acc0[mt][nt][0]; h0[1] = (_Float16)acc0[mt][nt][1];
            h0[2] = (_Float16)acc0[mt][nt][2]; h0[3] = (_Float16)acc0[mt][nt][3];
            h1[0] = (_Float16)acc1[mt][nt][0]; h1[1] = (_Float16)acc1[mt][nt][1];
            h1[2] = (_Float16)acc1[mt][nt][2]; h1[3] = (_Float16)acc1[mt][nt][3];
            *(f16x4*)((char*)xs0 + (byte ^ ((t & 7) << 4))) = h0;
            *(f16x4*)((char*)xs1 + (byte ^ ((t & 7) << 4))) = h1;
        }
    __syncthreads();

    // ---- Y2 copy: LDS -> global, interleaved, non-temporal ----
#pragma unroll
    for (int k = 0; k < 8; ++k) {
        int lin = k * 512 + tid;
        int t = lin >> 6;
        int v8 = (lin & 63) << 3;
        int byte = (t * V_ + v8) * 2;
        f16x8 s0 = *(const f16x8*)((const char*)xs0 + (byte ^ ((t & 7) << 4)));
        f16x8 s1 = *(const f16x8*)((const char*)xs1 + (byte ^ ((t & 7) << 4)));
        f16x8 lo, hi;
        lo[0] = s0[0]; lo[1] = s1[0]; lo[2] = s0[1]; lo[3] = s1[1];
        lo[4] = s0[2]; lo[5] = s1[2]; lo[6] = s0[3]; lo[7] = s1[3];
        hi[0] = s0[4]; hi[1] = s1[4]; hi[2] = s0[5]; hi[3] = s1[5];
        hi[4] = s0[6]; hi[5] = s1[6]; hi[6] = s0[7]; hi[7] = s1[7];
        __builtin_nontemporal_store(lo, (f16x8*)&Y2i[((size_t)t * V_ + v8) * 2]);
        __builtin_nontemporal_store(hi, (f16x8*)&Y2i[((size_t)t * V_ + v8) * 2 + 8]);
    }
}

// ---------------------------------------------------------------------------
// Kernel 6: MFMA epilogue GEMM on pair-interleaved H: B-fragments via
// non-temporal f16x2 loads (read-once streaming).
// out[ng,o,v,t] = PReLU( bias[o] + sum_{k} Wcat[o,k] * H_k )
// ---------------------------------------------------------------------------
__global__ __launch_bounds__(256) void epi_kernel(
    const _Float16* __restrict__ H, unsigned long long ASZ,
    const _Float16* __restrict__ Wcat, const float* __restrict__ bias,
    const float* __restrict__ alpha_p, float* __restrict__ out, int n0)
{
    const int v0 = blockIdx.x * 32;
    const int t0 = blockIdx.y * 8;
    const int nl = blockIdx.z;
    const int ng = n0 + nl;
    const int tid = threadIdx.x;
    const int lane = tid & 63;
    const int wv = tid >> 6;      // wave 0..3 -> t pair
    const int row16 = lane & 15;
    const int kg = lane >> 4;

    f32x4 acc[2][2][4];           // [j: t][vs: v-half][mt: o-tile]
#pragma unroll
    for (int j = 0; j < 2; ++j)
#pragma unroll
        for (int vs = 0; vs < 2; ++vs)
#pragma unroll
            for (int mt = 0; mt < 4; ++mt) acc[j][vs][mt] = (f32x4){0.f, 0.f, 0.f, 0.f};

    // pair-chunk base: pair index (nl*16 + kg*4), element ((t)*V+v)*2
    const size_t pbI = ((size_t)(nl * 16 + kg * 4)) * 2 * TV_
                     + ((size_t)(t0 + wv * 2) * V_ + v0 + row16) * 2;

#pragma unroll
    for (int ks = 0; ks < 8; ++ks) {
        const _Float16* Hk = H + (size_t)ks * ASZ;
        f16x8 a[4];
#pragma unroll
        for (int mt = 0; mt < 4; ++mt)
            a[mt] = *(const f16x8*)(Wcat + (mt * 16 + row16) * 256 + ks * 32 + kg * 8);
#pragma unroll
        for (int j = 0; j < 2; ++j)
#pragma unroll
            for (int vs = 0; vs < 2; ++vs) {
                const _Float16* hp = Hk + pbI + ((size_t)j * V_ + vs * 16) * 2;
                f16x8 bf;
#pragma unroll
                for (int qq = 0; qq < 4; ++qq) {
                    f16x2 pr = __builtin_nontemporal_load(
                        (const f16x2*)(hp + (size_t)qq * 2 * TV_));
                    bf[2 * qq]     = pr[0];
                    bf[2 * qq + 1] = pr[1];
                }
#pragma unroll
                for (int mt = 0; mt < 4; ++mt)
                    acc[j][vs][mt] = __builtin_amdgcn_mfma_f32_16x16x32_f16(a[mt], bf, acc[j][vs][mt], 0, 0, 0);
            }
    }

    // C transpose via LDS: sC[o16][v33-pad][t9-pad]
    __shared__ float sC[16 * 33 * 9];
    const float al = alpha_p[0];
    const int ot = tid >> 4;
    const int vvt = tid & 15;

    for (int mt = 0; mt < 4; ++mt) {
#pragma unroll
        for (int j = 0; j < 2; ++j)
#pragma unroll
            for (int vs = 0; vs < 2; ++vs)
#pragma unroll
                for (int r = 0; r < 4; ++r)
                    sC[((kg * 4 + r) * 33 + vs * 16 + row16) * 9 + wv * 2 + j] = acc[j][vs][mt][r];
        __syncthreads();
        const float bo = bias[mt * 16 + ot];
#pragma unroll
        for (int vh = 0; vh < 2; ++vh) {
            const int vl = vvt + vh * 16;
            float vals[8];
#pragma unroll
            for (int tt = 0; tt < 8; ++tt) {
                float u = sC[(ot * 33 + vl) * 9 + tt] + bo;
                vals[tt] = u > 0.f ? u : al * u;
            }
            float* op = out + (((size_t)ng * OC_ + mt * 16 + ot) * V_ + v0 + vl) * T_ + t0;
            *(float4*)&op[0] = make_float4(vals[0], vals[1], vals[2], vals[3]);
            *(float4*)&op[4] = make_float4(vals[4], vals[5], vals[6], vals[7]);
        }
        __syncthreads();
    }
}

// ---------------------------------------------------------------------------
extern "C" void kernel_launch(void* const* d_in, const int* in_sizes, int n_in,
                              void* d_out, int out_size, void* d_ws, size_t ws_size,
                              hipStream_t stream)
{
    const float* x       = (const float*)d_in[0];
    const float* t_in    = (const float*)d_in[1];
    const float* A0      = (const float*)d_in[2];
    const float* A1      = (const float*)d_in[3];
    const float* A2      = (const float*)d_in[4];
    const float* factors = (const float*)d_in[5];
    const float* Wq      = (const float*)d_in[6];
    const float* Wk      = (const float*)d_in[7];
    const float* W_out   = (const float*)d_in[8];
    const float* b_out   = (const float*)d_in[9];
    const float* W_res   = (const float*)d_in[10];
    const float* b_res   = (const float*)d_in[11];
    const float* gamma   = (const float*)d_in[12];
    const float* beta    = (const float*)d_in[13];
    const float* mean    = (const float*)d_in[14];
    const float* var     = (const float*)d_in[15];
    const float* alpha   = (const float*)d_in[16];
    float* out = (float*)d_out;

    float* att = (float*)d_ws;                               // 262144 f32
    float* S    = att + (size_t)N_ * H_ * T_ * T_;           // 65536 f32
    float* bias = S + (size_t)N_ * T_ * T_;                  // 64 f32
    _Float16* At16 = (_Float16*)(bias + 64);                 // 3*V*V f16
    _Float16* Wcat = At16 + (size_t)3 * V_ * V_;             // 64*256 f16
    _Float16* Hbase = Wcat + (size_t)64 * 256;               // 8 chunk arrays

    const size_t fixed = ((size_t)N_ * H_ * T_ * T_ + (size_t)N_ * T_ * T_ + 64) * 4
                       + ((size_t)3 * V_ * V_ + 64 * 256) * 2;
    int Nc = 16;
    while (Nc > 1 && fixed + (size_t)8 * Nc * C_ * T_ * V_ * 2 > ws_size) Nc >>= 1;
    const size_t ASZ = (size_t)Nc * C_ * T_ * V_;   // elements per chunk array

    att_kernel<<<N_ * H_, 64, 0, stream>>>(t_in, factors, Wq, Wk, att);
    sred_kernel<<<(N_ * T_ * T_ + 255) / 256, 256, 0, stream>>>(att, S);
    prepAt_kernel<<<dim3(16, 16, 3), 256, 0, stream>>>(A0, A1, A2, At16);
    prepW_kernel<<<1, 256, 0, stream>>>(W_out, b_out, W_res, b_res,
                                        gamma, beta, mean, var, Wcat, bias);

    for (int n0 = 0; n0 < N_; n0 += Nc) {
        const int nsl = Nc * C_;
        xtT_kernel<<<dim3(2, nsl / 2), 256, 0, stream>>>(x, S, Hbase, n0);
        prepxT_kernel<<<dim3(16, 2, nsl / 2), 256, 0, stream>>>(x, Hbase + (size_t)7 * ASZ, n0);
        hopf_kernel<<<dim3(nsl / 2, 3), 512, 0, stream>>>(At16, Hbase, (unsigned long long)ASZ);
        epi_kernel<<<dim3(16, 8, Nc), 256, 0, stream>>>(
            Hbase, (unsigned long long)ASZ, Wcat, bias, alpha, out, n0);
    }
}

// Round 17
// 453.395 us; speedup vs baseline: 1.0174x; 1.0174x over previous
//
#include <hip/hip_runtime.h>

namespace {
constexpr int N_ = 16, C_ = 32, V_ = 512, T_ = 64;
constexpr int H_ = 4, D_ = 16, OC_ = 64;
constexpr int EMB_ = 64;
constexpr int GCIN_ = 7 * C_;         // 224
constexpr int TV_ = T_ * V_;          // 32768 elements per slice
}

typedef _Float16 f16x8 __attribute__((ext_vector_type(8)));
typedef _Float16 f16x4 __attribute__((ext_vector_type(4)));
typedef _Float16 f16x2 __attribute__((ext_vector_type(2)));
typedef float f32x4 __attribute__((ext_vector_type(4)));

// ---------------------------------------------------------------------------
// Kernel 1: per-(n,h) attention rows. att[n,h,t,p] = softmax_p(q_t . k_p / 4)
// ---------------------------------------------------------------------------
__global__ __launch_bounds__(64) void att_kernel(
    const float* __restrict__ t_in, const float* __restrict__ factors,
    const float* __restrict__ Wq, const float* __restrict__ Wk,
    float* __restrict__ att)
{
    const int n = blockIdx.x >> 2;
    const int h = blockIdx.x & 3;
    const int t = threadIdx.x;   // 0..63

    __shared__ float wq_l[EMB_][D_];
    __shared__ float wk_l[EMB_][D_];
    __shared__ float k_l[T_][D_ + 1];

#pragma unroll
    for (int d = 0; d < D_; ++d) {
        wq_l[t][d] = Wq[(h * EMB_ + t) * D_ + d];
        wk_l[t][d] = Wk[(h * EMB_ + t) * D_ + d];
    }
    __syncthreads();

    const float tv = t_in[n * T_ + t];
    const float fh = factors[h];
    float emb[EMB_];
#pragma unroll
    for (int j = 0; j < 32; ++j) {
        float dt = __expf((float)(2 * j) * fh);
        float ph = tv * dt;
        float s, c;
        __sincosf(ph, &s, &c);
        emb[j] = s;
        emb[j + 32] = c;
    }

    float q[D_];
#pragma unroll
    for (int d = 0; d < D_; ++d) {
        float aq = 0.f, ak = 0.f;
#pragma unroll
        for (int f = 0; f < EMB_; ++f) {
            aq += emb[f] * wq_l[f][d];
            ak += emb[f] * wk_l[f][d];
        }
        q[d] = aq;
        k_l[t][d] = ak;
    }
    __syncthreads();

    float L[T_];
    float m = -1e30f;
#pragma unroll
    for (int j = 0; j < T_; ++j) {
        float a = 0.f;
#pragma unroll
        for (int d = 0; d < D_; ++d) a += q[d] * k_l[j][d];
        a *= 0.25f;
        L[j] = a;
        m = fmaxf(m, a);
    }
    float ssum = 0.f;
#pragma unroll
    for (int j = 0; j < T_; ++j) {
        float e = __expf(L[j] - m);
        L[j] = e;
        ssum += e;
    }
    const float inv = 1.f / ssum;
    float* arow = att + (((size_t)(n * H_ + h) * T_ + t) * T_);
#pragma unroll
    for (int j = 0; j < T_; ++j) arow[j] = L[j] * inv;
}

// ---------------------------------------------------------------------------
// Kernel 2: S[n,i,j] = sum_h att[n,h,i,j]
// ---------------------------------------------------------------------------
__global__ __launch_bounds__(256) void sred_kernel(
    const float* __restrict__ att, float* __restrict__ S)
{
    int g = blockIdx.x * 256 + threadIdx.x;
    if (g >= N_ * T_ * T_) return;
    int n = g / (T_ * T_);
    int ij = g - n * (T_ * T_);
    float a = 0.f;
#pragma unroll
    for (int h = 0; h < H_; ++h) a += att[(size_t)(n * H_ + h) * (T_ * T_) + ij];
    S[g] = a;
}

// ---------------------------------------------------------------------------
// Kernel 3: At16[s][w][v] = (f16) A_s[v][w]   (transpose + cast)
// ---------------------------------------------------------------------------
__global__ __launch_bounds__(256) void prepAt_kernel(
    const float* __restrict__ A0, const float* __restrict__ A1,
    const float* __restrict__ A2, _Float16* __restrict__ At16)
{
    const int s = blockIdx.z;
    const float* A = (s == 0) ? A0 : ((s == 1) ? A1 : A2);
    const int v0 = blockIdx.y * 32, w0 = blockIdx.x * 32;
    const int tid = threadIdx.x;
    __shared__ float sT[32][33];
#pragma unroll
    for (int k = 0; k < 4; ++k) {
        int lin = k * 256 + tid;
        int i = lin >> 5, w = lin & 31;
        sT[i][w] = A[(size_t)(v0 + i) * V_ + w0 + w];
    }
    __syncthreads();
#pragma unroll
    for (int k = 0; k < 4; ++k) {
        int lin = k * 256 + tid;
        int j = lin >> 5, i = lin & 31;
        At16[(size_t)s * V_ * V_ + (size_t)(w0 + j) * V_ + v0 + i] = (_Float16)sT[i][j];
    }
}

// ---------------------------------------------------------------------------
// Kernel 3b: residual channels, channel-PAIR interleaved:
// xT[q][t][v][sl] = (f16) x[n0*C + 2q+sl][v][t]
// ---------------------------------------------------------------------------
__global__ __launch_bounds__(256) void prepxT_kernel(
    const float* __restrict__ x, _Float16* __restrict__ xT, int n0)
{
    const int q = blockIdx.z;            // pair index within chunk
    const int v0 = blockIdx.x * 32;
    const int t0 = blockIdx.y * 32;
    const int tid = threadIdx.x;
    __shared__ float sT0[32][33];
    __shared__ float sT1[32][33];
    const float* xb0 = x + ((size_t)(n0 * C_) + 2 * q) * (size_t)(V_ * T_);
    const float* xb1 = xb0 + (size_t)(V_ * T_);
    {
        int vi = tid >> 3, tq = tid & 7;
        *(float4*)&sT0[vi][tq * 4] = *(const float4*)&xb0[(size_t)(v0 + vi) * T_ + t0 + tq * 4];
        *(float4*)&sT1[vi][tq * 4] = *(const float4*)&xb1[(size_t)(v0 + vi) * T_ + t0 + tq * 4];
    }
    __syncthreads();
    {
        int tj = tid >> 3, vq = tid & 7;
        f16x8 o;
#pragma unroll
        for (int j = 0; j < 4; ++j) {
            o[2 * j]     = (_Float16)sT0[vq * 4 + j][tj];
            o[2 * j + 1] = (_Float16)sT1[vq * 4 + j][tj];
        }
        *(f16x8*)&xT[(size_t)q * 2 * TV_ + ((size_t)(t0 + tj) * V_ + v0 + vq * 4) * 2] = o;
    }
}

// ---------------------------------------------------------------------------
// Kernel 3c: Wcat[o][k] f16 (k<224: W_out; k>=224: BN-scaled W_res), bias[o].
// ---------------------------------------------------------------------------
__global__ __launch_bounds__(256) void prepW_kernel(
    const float* __restrict__ W_out, const float* __restrict__ b_out,
    const float* __restrict__ W_res, const float* __restrict__ b_res,
    const float* __restrict__ gamma, const float* __restrict__ beta,
    const float* __restrict__ mean, const float* __restrict__ var,
    _Float16* __restrict__ Wcat, float* __restrict__ bias)
{
    const int tid = threadIdx.x;
    const int o = tid & 63;
    const int kb = tid >> 6;   // 0..3
    const float rs = gamma[o] * rsqrtf(var[o] + 1e-5f);
    for (int kk = 0; kk < 64; ++kk) {
        int k = kb * 64 + kk;
        float w = (k < GCIN_) ? W_out[o * GCIN_ + k] : rs * W_res[o * C_ + (k - GCIN_)];
        Wcat[o * 256 + k] = (_Float16)w;
    }
    if (tid < 64) bias[tid] = b_out[tid] + beta[tid] + rs * (b_res[tid] - mean[tid]);
}

// ---------------------------------------------------------------------------
// Kernel 4: xtT paired: for pair q (slices 2q, 2q+1 sharing n = q>>4):
// XT[q][p][v][sl] = sum_j S[n][p][j] * x[2q+sl][v][j]. B(S) shared by both.
// ---------------------------------------------------------------------------
__global__ __launch_bounds__(256) void xtT_kernel(
    const float* __restrict__ x, const float* __restrict__ S,
    _Float16* __restrict__ XT, int n0)
{
    const int q = blockIdx.y;            // pair index within chunk
    const int n = q >> 4;
    const int lane = threadIdx.x & 63;
    const int wav = threadIdx.x >> 6;
    const int vbase = blockIdx.x * 256 + wav * 64;
    const int row16 = lane & 15;
    const int kg = lane >> 4;

    const float* Sn = S + (size_t)(n0 + n) * (T_ * T_);
    const float* xb0 = x + ((size_t)(n0 * C_) + 2 * q) * (size_t)(V_ * T_);
    const float* xb1 = xb0 + (size_t)(V_ * T_);

    f32x4 acc0[4][4], acc1[4][4];
#pragma unroll
    for (int i = 0; i < 4; ++i)
#pragma unroll
        for (int j = 0; j < 4; ++j) {
            acc0[i][j] = (f32x4){0.f, 0.f, 0.f, 0.f};
            acc1[i][j] = (f32x4){0.f, 0.f, 0.f, 0.f};
        }

#pragma unroll
    for (int ks = 0; ks < 2; ++ks) {
        f16x8 a0[4], a1[4], bf[4];
#pragma unroll
        for (int mt = 0; mt < 4; ++mt) {   // A = x rows (m = v), both slices
            const float* p0 = xb0 + (size_t)(vbase + mt * 16 + row16) * T_ + ks * 32 + kg * 8;
            const float* p1 = xb1 + (size_t)(vbase + mt * 16 + row16) * T_ + ks * 32 + kg * 8;
            float4 u0 = *(const float4*)p0, w0 = *(const float4*)(p0 + 4);
            float4 u1 = *(const float4*)p1, w1 = *(const float4*)(p1 + 4);
            f16x8 t0, t1;
            t0[0] = (_Float16)u0.x; t0[1] = (_Float16)u0.y; t0[2] = (_Float16)u0.z; t0[3] = (_Float16)u0.w;
            t0[4] = (_Float16)w0.x; t0[5] = (_Float16)w0.y; t0[6] = (_Float16)w0.z; t0[7] = (_Float16)w0.w;
            t1[0] = (_Float16)u1.x; t1[1] = (_Float16)u1.y; t1[2] = (_Float16)u1.z; t1[3] = (_Float16)u1.w;
            t1[4] = (_Float16)w1.x; t1[5] = (_Float16)w1.y; t1[6] = (_Float16)w1.z; t1[7] = (_Float16)w1.w;
            a0[mt] = t0; a1[mt] = t1;
        }
#pragma unroll
        for (int nt = 0; nt < 4; ++nt) {   // B = S rows (n = p), shared
            const float* p = Sn + (size_t)(nt * 16 + row16) * T_ + ks * 32 + kg * 8;
            float4 u = *(const float4*)p, w = *(const float4*)(p + 4);
            f16x8 t8;
            t8[0] = (_Float16)u.x; t8[1] = (_Float16)u.y; t8[2] = (_Float16)u.z; t8[3] = (_Float16)u.w;
            t8[4] = (_Float16)w.x; t8[5] = (_Float16)w.y; t8[6] = (_Float16)w.z; t8[7] = (_Float16)w.w;
            bf[nt] = t8;
        }
#pragma unroll
        for (int nt = 0; nt < 4; ++nt)
#pragma unroll
            for (int mt = 0; mt < 4; ++mt) {
                acc0[mt][nt] = __builtin_amdgcn_mfma_f32_16x16x32_f16(a0[mt], bf[nt], acc0[mt][nt], 0, 0, 0);
                acc1[mt][nt] = __builtin_amdgcn_mfma_f32_16x16x32_f16(a1[mt], bf[nt], acc1[mt][nt], 0, 0, 0);
            }
    }

    _Float16* Yq = XT + (size_t)q * 2 * TV_;
#pragma unroll
    for (int mt = 0; mt < 4; ++mt)
#pragma unroll
        for (int nt = 0; nt < 4; ++nt) {
            int p = nt * 16 + row16;
            int v = vbase + mt * 16 + kg * 4;
            f16x8 h;
#pragma unroll
            for (int r = 0; r < 4; ++r) {
                h[2 * r]     = (_Float16)acc0[mt][nt][r];
                h[2 * r + 1] = (_Float16)acc1[mt][nt][r];
            }
            *(f16x8*)&Yq[((size_t)p * V_ + v) * 2] = h;
        }
}

// ---------------------------------------------------------------------------
// Kernel 5: fused double diffusion hop, pair-per-block, interleaved I/O.
// Chain: stage(de-interleave) -> bar -> hop1 -> bar -> x1->LDS -> bar ->
//        Y1 interleaved 16B stores -> hop2 -> Y2 stores.  (R11, measured best)
// ---------------------------------------------------------------------------
__global__ __launch_bounds__(512) void hopf_kernel(
    const _Float16* __restrict__ At16, _Float16* __restrict__ Hb,
    unsigned long long ASZ)
{
    const int bp = blockIdx.x;  // pair
    const int s = blockIdx.y;   // support
    const int tid = threadIdx.x;
    const int lane = tid & 63;
    const int wav = tid >> 6;
    const int wbase = wav * 64;
    const int row16 = lane & 15;
    const int kg = lane >> 4;

    __shared__ _Float16 xs0[T_ * V_];   // 64 KiB (slice 0)
    __shared__ _Float16 xs1[T_ * V_];   // 64 KiB (slice 1)

    const _Float16* At = At16 + (size_t)s * V_ * V_;
    const _Float16* Xi = Hb + (size_t)bp * 2 * TV_;                     // interleaved
    _Float16* Y1i = Hb + (size_t)(1 + 2 * s) * ASZ + (size_t)bp * 2 * TV_;
    _Float16* Y2i = Hb + (size_t)(2 + 2 * s) * ASZ + (size_t)bp * 2 * TV_;

    const _Float16* ax = At + (size_t)(wbase + row16) * V_ + kg * 8;

    f32x4 acc0[4][4], acc1[4][4];
    f16x8 aC[4], aN[4];

    // ---- stage: read interleaved pair, de-interleave into xs0/xs1 ----
#pragma unroll
    for (int k = 0; k < 8; ++k) {
        int lin = k * 512 + tid;
        int t = lin >> 6;
        int v8 = (lin & 63) << 3;
        const f16x8 lo = *(const f16x8*)&Xi[((size_t)t * V_ + v8) * 2];
        const f16x8 hi = *(const f16x8*)&Xi[((size_t)t * V_ + v8) * 2 + 8];
        f16x8 s0, s1;
        s0[0] = lo[0]; s0[1] = lo[2]; s0[2] = lo[4]; s0[3] = lo[6];
        s0[4] = hi[0]; s0[5] = hi[2]; s0[6] = hi[4]; s0[7] = hi[6];
        s1[0] = lo[1]; s1[1] = lo[3]; s1[2] = lo[5]; s1[3] = lo[7];
        s1[4] = hi[1]; s1[5] = hi[3]; s1[6] = hi[5]; s1[7] = hi[7];
        int byte = (t * V_ + v8) * 2;
        *(f16x8*)((char*)xs0 + (byte ^ ((t & 7) << 4))) = s0;
        *(f16x8*)((char*)xs1 + (byte ^ ((t & 7) << 4))) = s1;
    }
    __syncthreads();

    // ---- hop 1: A global (2-deep), B from both LDS tiles ----
#pragma unroll
    for (int i = 0; i < 4; ++i)
#pragma unroll
        for (int j = 0; j < 4; ++j) {
            acc0[i][j] = (f32x4){0.f, 0.f, 0.f, 0.f};
            acc1[i][j] = (f32x4){0.f, 0.f, 0.f, 0.f};
        }
#pragma unroll
    for (int i = 0; i < 4; ++i)
        aC[i] = *(const f16x8*)(ax + (size_t)i * 16 * V_);

#pragma unroll
    for (int it = 0; it < 16; ++it) {
        const int v0 = it * 32;
        if (it < 15) {
#pragma unroll
            for (int i = 0; i < 4; ++i)
                aN[i] = *(const f16x8*)(ax + (size_t)i * 16 * V_ + v0 + 32);
        }
        f16x8 b0v[4], b1v[4];
#pragma unroll
        for (int nt = 0; nt < 4; ++nt) {
            int t = nt * 16 + row16;
            int byte = (t * V_ + v0 + kg * 8) * 2;
            b0v[nt] = *(const f16x8*)((const char*)xs0 + (byte ^ ((t & 7) << 4)));
            b1v[nt] = *(const f16x8*)((const char*)xs1 + (byte ^ ((t & 7) << 4)));
        }
#pragma unroll
        for (int nt = 0; nt < 4; ++nt)
#pragma unroll
            for (int mt = 0; mt < 4; ++mt) {
                acc0[mt][nt] = __builtin_amdgcn_mfma_f32_16x16x32_f16(aC[mt], b0v[nt], acc0[mt][nt], 0, 0, 0);
                acc1[mt][nt] = __builtin_amdgcn_mfma_f32_16x16x32_f16(aC[mt], b1v[nt], acc1[mt][nt], 0, 0, 0);
            }
#pragma unroll
        for (int i = 0; i < 4; ++i) aC[i] = aN[i];
    }
    __syncthreads();   // all X LDS reads done before overwrite

    // ---- x1 -> LDS (8B swizzled writes, per-slice layout for hop2) ----
#pragma unroll
    for (int mt = 0; mt < 4; ++mt)
#pragma unroll
        for (int nt = 0; nt < 4; ++nt) {
            int t = nt * 16 + row16;
            int w = wbase + mt * 16 + kg * 4;
            int byte = (t * V_ + w) * 2;
            f16x4 h0, h1;
            h0[0] = (_Float16)acc0[mt][nt][0]; h0[1] = (_Float16)acc0[mt][nt][1];
            h0[2] = (_Float16)acc0[mt][nt][2]; h0[3] = (_Float16)acc0[mt][nt][3];
            h1[0] = (_Float16)acc1[mt][nt][0]; h1[1] = (_Float16)acc1[mt][nt][1];
            h1[2] = (_Float16)acc1[mt][nt][2]; h1[3] = (_Float16)acc1[mt][nt][3];
            *(f16x4*)((char*)xs0 + (byte ^ ((t & 7) << 4))) = h0;
            *(f16x4*)((char*)xs1 + (byte ^ ((t & 7) << 4))) = h1;
        }
    __syncthreads();

    // ---- Y1: interleaved 16B direct stores (full 64B sectors per t-row) ----
#pragma unroll
    for (int mt = 0; mt < 4; ++mt)
#pragma unroll
        for (int nt = 0; nt < 4; ++nt) {
            int t = nt * 16 + row16;
            int w = wbase + mt * 16 + kg * 4;
            f16x8 h;
#pragma unroll
            for (int r = 0; r < 4; ++r) {
                h[2 * r]     = (_Float16)acc0[mt][nt][r];
                h[2 * r + 1] = (_Float16)acc1[mt][nt][r];
            }
            *(f16x8*)&Y1i[((size_t)t * V_ + w) * 2] = h;
        }

    // ---- hop 2: A global (2-deep), B = x1 from both LDS tiles ----
#pragma unroll
    for (int i = 0; i < 4; ++i)
#pragma unroll
        for (int j = 0; j < 4; ++j) {
            acc0[i][j] = (f32x4){0.f, 0.f, 0.f, 0.f};
            acc1[i][j] = (f32x4){0.f, 0.f, 0.f, 0.f};
        }
#pragma unroll
    for (int i = 0; i < 4; ++i)
        aC[i] = *(const f16x8*)(ax + (size_t)i * 16 * V_);

#pragma unroll
    for (int it = 0; it < 16; ++it) {
        const int v0 = it * 32;
        if (it < 15) {
#pragma unroll
            for (int i = 0; i < 4; ++i)
                aN[i] = *(const f16x8*)(ax + (size_t)i * 16 * V_ + v0 + 32);
        }
        f16x8 b0v[4], b1v[4];
#pragma unroll
        for (int nt = 0; nt < 4; ++nt) {
            int t = nt * 16 + row16;
            int byte = (t * V_ + v0 + kg * 8) * 2;
            b0v[nt] = *(const f16x8*)((const char*)xs0 + (byte ^ ((t & 7) << 4)));
            b1v[nt] = *(const f16x8*)((const char*)xs1 + (byte ^ ((t & 7) << 4)));
        }
#pragma unroll
        for (int nt = 0; nt < 4; ++nt)
#pragma unroll
            for (int mt = 0; mt < 4; ++mt) {
                acc0[mt][nt] = __builtin_amdgcn_mfma_f32_16x16x32_f16(aC[mt], b0v[nt], acc0[mt][nt], 0, 0, 0);
                acc1[mt][nt] = __builtin_amdgcn_mfma_f32_16x16x32_f16(aC[mt], b1v[nt], acc1[mt][nt], 0, 0, 0);
            }
#pragma unroll
        for (int i = 0; i < 4; ++i) aC[i] = aN[i];
    }

    // ---- Y2: interleaved 16B direct stores ----
#pragma unroll
    for (int mt = 0; mt < 4; ++mt)
#pragma unroll
        for (int nt = 0; nt < 4; ++nt) {
            int t = nt * 16 + row16;
            int w = wbase + mt * 16 + kg * 4;
            f16x8 h;
#pragma unroll
            for (int r = 0; r < 4; ++r) {
                h[2 * r]     = (_Float16)acc0[mt][nt][r];
                h[2 * r + 1] = (_Float16)acc1[mt][nt][r];
            }
            *(f16x8*)&Y2i[((size_t)t * V_ + w) * 2] = h;
        }
}

// ---------------------------------------------------------------------------
// Kernel 6: MFMA epilogue GEMM on pair-interleaved H: B-fragments via f16x2.
// out[ng,o,v,t] = PReLU( bias[o] + sum_{k} Wcat[o,k] * H_k )
// ---------------------------------------------------------------------------
__global__ __launch_bounds__(256) void epi_kernel(
    const _Float16* __restrict__ H, unsigned long long ASZ,
    const _Float16* __restrict__ Wcat, const float* __restrict__ bias,
    const float* __restrict__ alpha_p, float* __restrict__ out, int n0)
{
    const int v0 = blockIdx.x * 32;
    const int t0 = blockIdx.y * 8;
    const int nl = blockIdx.z;
    const int ng = n0 + nl;
    const int tid = threadIdx.x;
    const int lane = tid & 63;
    const int wv = tid >> 6;      // wave 0..3 -> t pair
    const int row16 = lane & 15;
    const int kg = lane >> 4;

    f32x4 acc[2][2][4];           // [j: t][vs: v-half][mt: o-tile]
#pragma unroll
    for (int j = 0; j < 2; ++j)
#pragma unroll
        for (int vs = 0; vs < 2; ++vs)
#pragma unroll
            for (int mt = 0; mt < 4; ++mt) acc[j][vs][mt] = (f32x4){0.f, 0.f, 0.f, 0.f};

    // pair-chunk base: pair index (nl*16 + kg*4), element ((t)*V+v)*2
    const size_t pbI = ((size_t)(nl * 16 + kg * 4)) * 2 * TV_
                     + ((size_t)(t0 + wv * 2) * V_ + v0 + row16) * 2;

#pragma unroll
    for (int ks = 0; ks < 8; ++ks) {
        const _Float16* Hk = H + (size_t)ks * ASZ;
        f16x8 a[4];
#pragma unroll
        for (int mt = 0; mt < 4; ++mt)
            a[mt] = *(const f16x8*)(Wcat + (mt * 16 + row16) * 256 + ks * 32 + kg * 8);
#pragma unroll
        for (int j = 0; j < 2; ++j)
#pragma unroll
            for (int vs = 0; vs < 2; ++vs) {
                const _Float16* hp = Hk + pbI + ((size_t)j * V_ + vs * 16) * 2;
                f16x8 bf;
#pragma unroll
                for (int qq = 0; qq < 4; ++qq) {
                    f16x2 pr = *(const f16x2*)(hp + (size_t)qq * 2 * TV_);
                    bf[2 * qq]     = pr[0];
                    bf[2 * qq + 1] = pr[1];
                }
#pragma unroll
                for (int mt = 0; mt < 4; ++mt)
                    acc[j][vs][mt] = __builtin_amdgcn_mfma_f32_16x16x32_f16(a[mt], bf, acc[j][vs][mt], 0, 0, 0);
            }
    }

    // C transpose via LDS: sC[o16][v33-pad][t9-pad]
    __shared__ float sC[16 * 33 * 9];
    const float al = alpha_p[0];
    const int ot = tid >> 4;
    const int vvt = tid & 15;

    for (int mt = 0; mt < 4; ++mt) {
#pragma unroll
        for (int j = 0; j < 2; ++j)
#pragma unroll
            for (int vs = 0; vs < 2; ++vs)
#pragma unroll
                for (int r = 0; r < 4; ++r)
                    sC[((kg * 4 + r) * 33 + vs * 16 + row16) * 9 + wv * 2 + j] = acc[j][vs][mt][r];
        __syncthreads();
        const float bo = bias[mt * 16 + ot];
#pragma unroll
        for (int vh = 0; vh < 2; ++vh) {
            const int vl = vvt + vh * 16;
            float vals[8];
#pragma unroll
            for (int tt = 0; tt < 8; ++tt) {
                float u = sC[(ot * 33 + vl) * 9 + tt] + bo;
                vals[tt] = u > 0.f ? u : al * u;
            }
            float* op = out + (((size_t)ng * OC_ + mt * 16 + ot) * V_ + v0 + vl) * T_ + t0;
            *(float4*)&op[0] = make_float4(vals[0], vals[1], vals[2], vals[3]);
            *(float4*)&op[4] = make_float4(vals[4], vals[5], vals[6], vals[7]);
        }
        __syncthreads();
    }
}

// ---------------------------------------------------------------------------
extern "C" void kernel_launch(void* const* d_in, const int* in_sizes, int n_in,
                              void* d_out, int out_size, void* d_ws, size_t ws_size,
                              hipStream_t stream)
{
    const float* x       = (const float*)d_in[0];
    const float* t_in    = (const float*)d_in[1];
    const float* A0      = (const float*)d_in[2];
    const float* A1      = (const float*)d_in[3];
    const float* A2      = (const float*)d_in[4];
    const float* factors = (const float*)d_in[5];
    const float* Wq      = (const float*)d_in[6];
    const float* Wk      = (const float*)d_in[7];
    const float* W_out   = (const float*)d_in[8];
    const float* b_out   = (const float*)d_in[9];
    const float* W_res   = (const float*)d_in[10];
    const float* b_res   = (const float*)d_in[11];
    const float* gamma   = (const float*)d_in[12];
    const float* beta    = (const float*)d_in[13];
    const float* mean    = (const float*)d_in[14];
    const float* var     = (const float*)d_in[15];
    const float* alpha   = (const float*)d_in[16];
    float* out = (float*)d_out;

    float* att = (float*)d_ws;                               // 262144 f32
    float* S    = att + (size_t)N_ * H_ * T_ * T_;           // 65536 f32
    float* bias = S + (size_t)N_ * T_ * T_;                  // 64 f32
    _Float16* At16 = (_Float16*)(bias + 64);                 // 3*V*V f16
    _Float16* Wcat = At16 + (size_t)3 * V_ * V_;             // 64*256 f16
    _Float16* Hbase = Wcat + (size_t)64 * 256;               // 8 chunk arrays

    const size_t fixed = ((size_t)N_ * H_ * T_ * T_ + (size_t)N_ * T_ * T_ + 64) * 4
                       + ((size_t)3 * V_ * V_ + 64 * 256) * 2;
    int Nc = 16;
    while (Nc > 1 && fixed + (size_t)8 * Nc * C_ * T_ * V_ * 2 > ws_size) Nc >>= 1;
    const size_t ASZ = (size_t)Nc * C_ * T_ * V_;   // elements per chunk array

    att_kernel<<<N_ * H_, 64, 0, stream>>>(t_in, factors, Wq, Wk, att);
    sred_kernel<<<(N_ * T_ * T_ + 255) / 256, 256, 0, stream>>>(att, S);
    prepAt_kernel<<<dim3(16, 16, 3), 256, 0, stream>>>(A0, A1, A2, At16);
    prepW_kernel<<<1, 256, 0, stream>>>(W_out, b_out, W_res, b_res,
                                        gamma, beta, mean, var, Wcat, bias);

    for (int n0 = 0; n0 < N_; n0 += Nc) {
        const int nsl = Nc * C_;
        xtT_kernel<<<dim3(2, nsl / 2), 256, 0, stream>>>(x, S, Hbase, n0);
        prepxT_kernel<<<dim3(16, 2, nsl / 2), 256, 0, stream>>>(x, Hbase + (size_t)7 * ASZ, n0);
        hopf_kernel<<<dim3(nsl / 2, 3), 512, 0, stream>>>(At16, Hbase, (unsigned long long)ASZ);
        epi_kernel<<<dim3(16, 8, Nc), 256, 0, stream>>>(
            Hbase, (unsigned long long)ASZ, Wcat, bias, alpha, out, n0);
    }
}